// Round 13
// baseline (1168.112 us; speedup 1.0000x reference)
//
#include <hip/hip_runtime.h>

namespace {

constexpr int T = 465;        // (N-1)(N-2)/2 triplets per center
constexpr float FCUT = 3.5f;
constexpr float PI_OVER_CUT = 0.8975979010256552f; // pi/3.5
constexpr int REC = 12;       // floats per compacted row record
constexpr int K2_GRID = 1024; // 1-wave blocks
constexpr int MAXROWS_HARD = 1024 * 480;

// 16-float vector in CONSTANT address space -> s_load_dwordx16 (scalar pipe).
typedef float __attribute__((ext_vector_type(16))) f16v;
typedef const __attribute__((address_space(4))) f16v* c16p;

__device__ __forceinline__ float ftanh(float x) {
    x = fminf(fmaxf(x, -15.0f), 15.0f);
    const float e = __expf(2.0f * x);
    return (e - 1.0f) * __builtin_amdgcn_rcpf(e + 1.0f);
}

// closed-form unrank of t in [0,465) -> pair (a,b), 0<=a<b<31 (M=31)
__device__ __forceinline__ void unrank(int t, int i, int& j, int& k) {
    int a = (int)((61.0f - sqrtf(3721.0f - 8.0f * (float)t)) * 0.5f);
    a = a < 0 ? 0 : (a > 29 ? 29 : a);
    int rem = t - ((a * (61 - a)) >> 1);
    while (rem < 0) { --a; rem = t - ((a * (61 - a)) >> 1); }
    while (rem >= 30 - a) { rem -= 30 - a; ++a; }
    const int b = a + 1 + rem;
    j = a + (a >= i);
    k = b + (b >= i);
}

// ---------------- K1: compact active triplets into global row list ----------
__global__ __launch_bounds__(256, 4)
void feat_kernel(const float* __restrict__ D, const float* __restrict__ Z,
                 float* __restrict__ rows, int* __restrict__ ctr, int maxrows)
{
    const int lane = threadIdx.x & 63;
    const int center = blockIdx.x * 4 + (threadIdx.x >> 6);
    const int bi = center >> 5, i = center & 31;
    const float* __restrict__ Drow = D + bi * 1024;
    const float* __restrict__ Zrow = Z + bi * 32;
    const float z_i = Zrow[i];

    unsigned long long masks[8];
    int cnt = 0;
    #pragma unroll
    for (int rnd = 0; rnd < 8; ++rnd) {
        const int t = rnd * 64 + lane;
        bool act = false;
        if (t < T) {
            int j, k;
            unrank(t, i, j, k);
            const float rij = Drow[i * 32 + j];
            const float rik = Drow[i * 32 + k];
            act = (rij < FCUT) && (rik < FCUT);
        }
        masks[rnd] = __ballot(act);
        cnt += (int)__popcll(masks[rnd]);
    }
    const int padded = (cnt + 15) & ~15;   // every 16-segment belongs to one center
    if (padded == 0) return;
    int base = 0;
    if (lane == 0) base = atomicAdd(ctr, padded);
    base = __shfl(base, 0);
    if (base + padded > maxrows) return;

    int pre = 0;
    #pragma unroll
    for (int rnd = 0; rnd < 8; ++rnd) {
        const unsigned long long mb = masks[rnd];
        const bool act = (mb >> lane) & 1ull;
        const int slot = base + pre + (int)__popcll(mb & ((1ull << lane) - 1ull));
        pre += (int)__popcll(mb);
        if (act) {
            const int t = rnd * 64 + lane;
            int j, k;
            unrank(t, i, j, k);
            const float rij = Drow[i * 32 + j];
            const float rik = Drow[i * 32 + k];
            const float rjk = Drow[j * 32 + k];
            const float zj = Zrow[j], zk = Zrow[k];
            const float rij2 = rij * rij, rik2 = rik * rik, rjk2 = rjk * rjk;
            const float ci = (rij2 + rik2 - rjk2) * __builtin_amdgcn_rcpf(fmaxf(2.f * rij * rik, 1e-10f));
            const float cj = (rij2 + rjk2 - rik2) * __builtin_amdgcn_rcpf(fmaxf(2.f * rij * rjk, 1e-10f));
            const float ck = (rik2 + rjk2 - rij2) * __builtin_amdgcn_rcpf(fmaxf(2.f * rik * rjk, 1e-10f));
            const float g0 = rij + rik + rjk;
            const float g1 = rij * rik + rij * rjk + rik * rjk;
            const float g2 = rij * rik * rjk;
            const float rg = __builtin_amdgcn_rcpf(sqrtf(g0 * g0 + g1 * g1 + g2 * g2) + 1e-7f);
            const float s0 = z_i + zj + zk;
            const float s1 = ci + cj + ck;
            const float s2 = z_i * (zj + zk) + zj * zk - ci * (cj + ck) - cj * ck;
            const float s3 = z_i * (cj + ck) + ci * (zj + zk) + zj * ck + cj * zk;
            const float s4 = z_i * (zj * zk - cj * ck) - ci * (zj * ck + cj * zk);
            const float s5 = z_i * (zj * ck + cj * zk) + ci * (zj * zk - cj * ck);
            const float rs = __builtin_amdgcn_rcpf(sqrtf(s0*s0 + s1*s1 + s2*s2 + s3*s3 + s4*s4 + s5*s5) + 1e-7f);
            const float fij = 0.5f * __cosf(PI_OVER_CUT * rij) + 0.5f;
            const float fik = 0.5f * __cosf(PI_OVER_CUT * rik) + 0.5f;
            float4* dst = (float4*)(rows + (size_t)slot * REC);
            dst[0] = make_float4(g0 * rg, g1 * rg, g2 * rg, s0 * rs);
            dst[1] = make_float4(s1 * rs, s2 * rs, s3 * rs, s4 * rs);
            dst[2] = make_float4(s5 * rs, fij * fik, __int_as_float(center), 0.f);
        }
    }
    for (int p = cnt + lane; p < padded; p += 64) {
        float4* dst = (float4*)(rows + (size_t)(base + p) * REC);
        dst[0] = make_float4(0.f, 0.f, 0.f, 0.f);
        dst[1] = make_float4(0.f, 0.f, 0.f, 0.f);
        dst[2] = make_float4(0.f, 0.f, __int_as_float(center), 0.f);
    }
}

// acc[64] = biases (scalar loads)
__device__ __forceinline__ void bias64(const float* Bp, float (&acc)[64]) {
    c16p bp = (c16p)(uintptr_t)Bp;
    const f16v b0 = bp[0], b1 = bp[1], b2 = bp[2], b3 = bp[3];
    #pragma unroll
    for (int q = 0; q < 16; ++q) {
        acc[q] = b0[q]; acc[16 + q] = b1[q]; acc[32 + q] = b2[q]; acc[48 + q] = b3[q];
    }
}

// acc[c] += sum_k x[k] * W[k][c], c = 0..63. x is per-lane (lane = row);
// W rows fetched as 4x s_load_dwordx16 (wave-uniform -> scalar pipe). The
// only VALU work is the 64 FMAs per k. x[k] is a scratch load (vmcnt pipe,
// 1 op per 64 FMAs - deliberate rule-20 exception at 1:64 ratio).
template<int LDW>
__device__ __forceinline__ void layer64(const float* __restrict__ W,
                                        const float* x, float (&acc)[64])
{
    #pragma unroll 2
    for (int k = 0; k < 64; ++k) {
        c16p wp = (c16p)(uintptr_t)(W + (size_t)k * LDW);
        const f16v w0 = wp[0], w1 = wp[1], w2 = wp[2], w3 = wp[3];
        const float xv = x[k];
        #pragma unroll
        for (int q = 0; q < 16; ++q) {
            acc[q]      = fmaf(xv, w0[q], acc[q]);
            acc[16 + q] = fmaf(xv, w1[q], acc[16 + q]);
            acc[32 + q] = fmaf(xv, w2[q], acc[32 + q]);
            acc[48 + q] = fmaf(xv, w3[q], acc[48 + q]);
        }
    }
}

// ---------------- K2: MLP, lane = row, 64 rows (4 segments) per wave --------
// No LDS, no readlane, no shuffles except the final 16-row reduce.
__global__ __launch_bounds__(64)
void mlp_kernel(const float* __restrict__ rows, const int* __restrict__ ctr,
                const float* __restrict__ W0, const float* __restrict__ B0,
                const float* __restrict__ W1, const float* __restrict__ B1,
                const float* __restrict__ W2, const float* __restrict__ B2,
                const float* __restrict__ W3, const float* __restrict__ B3,
                const float* __restrict__ W4, const float* __restrict__ B4,
                const float* __restrict__ W5, const float* __restrict__ B5,
                const float* __restrict__ W6, const float* __restrict__ B6,
                float* __restrict__ out, int maxrows)
{
    const int lane = threadIdx.x;
    int nrows = *ctr;                 // multiple of 16
    if (nrows > maxrows) nrows = maxrows & ~15;

    for (int g = blockIdx.x; g * 64 < nrows; g += K2_GRID) {
        const int row = g * 64 + lane;
        float xin[9];
        float sm = 0.f;
        int ct = -1;
        if (row < nrows) {
            const float4* rp = (const float4*)(rows + (size_t)row * REC);
            const float4 a = rp[0], b = rp[1], c = rp[2];
            xin[0] = a.x; xin[1] = a.y; xin[2] = a.z; xin[3] = a.w;
            xin[4] = b.x; xin[5] = b.y; xin[6] = b.z; xin[7] = b.w;
            xin[8] = c.x; sm = c.y; ct = __float_as_int(c.z);
        } else {
            #pragma unroll
            for (int q = 0; q < 9; ++q) xin[q] = 0.f;
        }

        float x[64], xA[64], xB[64];   // runtime-k-indexed -> scratch (1:64)
        float res[64], acc[64];        // static-indexed -> VGPR

        // ---- L0: 9 -> 64 (k fully unrolled; xin stays in VGPRs) ----
        bias64(B0, acc);
        #pragma unroll
        for (int k = 0; k < 9; ++k) {
            c16p wp = (c16p)(uintptr_t)(W0 + k * 64);
            const f16v w0 = wp[0], w1 = wp[1], w2 = wp[2], w3 = wp[3];
            const float xv = xin[k];
            #pragma unroll
            for (int q = 0; q < 16; ++q) {
                acc[q]      = fmaf(xv, w0[q], acc[q]);
                acc[16 + q] = fmaf(xv, w1[q], acc[16 + q]);
                acc[32 + q] = fmaf(xv, w2[q], acc[32 + q]);
                acc[48 + q] = fmaf(xv, w3[q], acc[48 + q]);
            }
        }
        #pragma unroll
        for (int c = 0; c < 64; ++c) { const float v = ftanh(acc[c]); x[c] = v; res[c] = v; }

        // ---- L1 ; blk1 = tanh + x_res ----
        bias64(B1, acc);
        layer64<64>(W1, x, acc);
        #pragma unroll
        for (int c = 0; c < 64; ++c) { const float v = ftanh(acc[c]) + res[c]; x[c] = v; res[c] = v; }

        // ---- L2 ----
        bias64(B2, acc);
        layer64<64>(W2, x, acc);
        #pragma unroll
        for (int c = 0; c < 64; ++c) x[c] = ftanh(acc[c]);

        // ---- L3 ----
        bias64(B3, acc);
        layer64<64>(W3, x, acc);
        #pragma unroll
        for (int c = 0; c < 64; ++c) x[c] = ftanh(acc[c]);

        // ---- L4 ; blk2 = tanh + blk1 ----
        bias64(B4, acc);
        layer64<64>(W4, x, acc);
        #pragma unroll
        for (int c = 0; c < 64; ++c) x[c] = ftanh(acc[c]) + res[c];

        // ---- L5: 64 -> 128 (two 64-col halves) ----
        bias64(B5, acc);
        layer64<128>(W5, x, acc);
        #pragma unroll
        for (int c = 0; c < 64; ++c) xA[c] = ftanh(acc[c]);

        bias64(B5 + 64, acc);
        layer64<128>(W5 + 64, x, acc);
        #pragma unroll
        for (int c = 0; c < 64; ++c) xB[c] = ftanh(acc[c]);

        // ---- L6: 128 -> 256, 4 chunks of 64 cols; 16-row in-wave reduce ----
        #pragma unroll 1
        for (int ch = 0; ch < 4; ++ch) {
            const int c0 = ch * 64;
            bias64(B6 + c0, acc);
            layer64<256>(W6 + c0, xA, acc);
            layer64<256>(W6 + 64 * 256 + c0, xB, acc);
            #pragma unroll
            for (int c = 0; c < 64; ++c) {
                float v = ftanh(acc[c]) * sm;
                v += __shfl_xor(v, 1);
                v += __shfl_xor(v, 2);
                v += __shfl_xor(v, 4);
                v += __shfl_xor(v, 8);
                acc[c] = v;            // per-16-row-segment sum
            }
            if (((lane & 15) == 0) && ct >= 0) {
                float* __restrict__ op = out + (size_t)ct * 256 + c0;
                #pragma unroll
                for (int c = 0; c < 64; ++c) atomicAdd(op + c, acc[c]);
            }
        }
    }
}

} // namespace

extern "C" void kernel_launch(void* const* d_in, const int* in_sizes, int n_in,
                              void* d_out, int out_size, void* d_ws, size_t ws_size,
                              hipStream_t stream) {
    (void)in_sizes; (void)n_in;

    const float* D  = (const float*)d_in[0];
    const float* Z  = (const float*)d_in[1];
    const float* W0 = (const float*)d_in[2];  const float* B0 = (const float*)d_in[3];
    const float* W1 = (const float*)d_in[4];  const float* B1 = (const float*)d_in[5];
    const float* W2 = (const float*)d_in[6];  const float* B2 = (const float*)d_in[7];
    const float* W3 = (const float*)d_in[8];  const float* B3 = (const float*)d_in[9];
    const float* W4 = (const float*)d_in[10]; const float* B4 = (const float*)d_in[11];
    const float* W5 = (const float*)d_in[12]; const float* B5 = (const float*)d_in[13];
    const float* W6 = (const float*)d_in[14]; const float* B6 = (const float*)d_in[15];
    float* out = (float*)d_out;

    int* ctr = (int*)d_ws;
    float* rowbuf = (float*)((char*)d_ws + 64);
    size_t avail = (ws_size > 64) ? (ws_size - 64) / (REC * sizeof(float)) : 0;
    int maxrows = (int)((avail < (size_t)MAXROWS_HARD) ? avail : (size_t)MAXROWS_HARD);

    hipMemsetAsync(d_ws, 0, 64, stream);
    hipMemsetAsync(d_out, 0, sizeof(float) * (size_t)out_size, stream);

    feat_kernel<<<256, 256, 0, stream>>>(D, Z, rowbuf, ctr, maxrows);
    mlp_kernel<<<K2_GRID, 64, 0, stream>>>(rowbuf, ctr,
                                           W0, B0, W1, B1, W2, B2, W3, B3,
                                           W4, B4, W5, B5, W6, B6, out, maxrows);
}